// Round 2
// baseline (859.454 us; speedup 1.0000x reference)
//
#include <hip/hip_runtime.h>
#include <math.h>

#define C   128
#define BLK 1024
#define WPB (BLK / 64)   // 16 waves per block

__device__ __forceinline__ float4 f4add(float4 a, float4 b) {
    float4 r; r.x = a.x + b.x; r.y = a.y + b.y; r.z = a.z + b.z; r.w = a.w + b.w; return r;
}
__device__ __forceinline__ float4 f4shfl_xor(float4 v, int m) {
    float4 r;
    r.x = __shfl_xor(v.x, m, 64);
    r.y = __shfl_xor(v.y, m, 64);
    r.z = __shfl_xor(v.z, m, 64);
    r.w = __shfl_xor(v.w, m, 64);
    return r;
}

extern "C" __global__ __launch_bounds__(BLK)
void cba_wave_kernel(const float* __restrict__ x,
                     const float* __restrict__ W,
                     const int* __restrict__ batch,
                     float* __restrict__ out,
                     int N, int B, int totalWaves)
{
    __shared__ float4 sW4[C * C / 4];   // 64 KB, row-major rows k, float4 over cols

    const int t    = threadIdx.x;
    const int lane = t & 63;
    const int q    = lane & 31;   // in-half lane: owns channels/cols 4q..4q+3
    const int h    = lane >> 5;   // half 0/1

    // ---- one-time: W into LDS (coalesced float4), the only block barrier ----
    const float4* Wg = (const float4*)W;
#pragma unroll
    for (int i = 0; i < (C * C / 4) / BLK; ++i)       // 4 iters
        sW4[t + i * BLK] = Wg[t + i * BLK];
    __syncthreads();

    const int gw = blockIdx.x * WPB + (t >> 6);       // global wave id

    // ---- lane-parallel segment-boundary search (once per wave) ----
    // lane l (<32)  : start of segment (gw + l*totalWaves)
    // lane 32+l     : start of segment (gw + l*totalWaves + 1)  == its end
    long long tgt = (lane < 32)
        ? (long long)gw + (long long)lane * totalWaves
        : (long long)gw + (long long)(lane - 32) * totalWaves + 1;
    int target = (tgt > B) ? B : (int)tgt;
    int lo = 0, hi = N;
    while (lo < hi) {
        int mid = (lo + hi) >> 1;
        if (batch[mid] < target) lo = mid + 1; else hi = mid;
    }
    const int bs = lo;

    const float4* x4 = (const float4*)x;

    // ---- free-running per-wave segment loop ----
    int sb = 0;
    for (int b = gw; b < B; b += totalWaves, ++sb) {
        const int s = __shfl(bs, sb, 64);
        const int e = __shfl(bs, 32 + sb, 64);

        // pass 1: segment channel-sums. 2 rows in flight (one per half).
        float4 acc = {0.f, 0.f, 0.f, 0.f};
        for (int i = s + h; i < e; i += 2) {
            float4 v = x4[(size_t)i * 32 + q];
            acc.x += v.x; acc.y += v.y; acc.z += v.z; acc.w += v.w;
        }
        acc = f4add(acc, f4shfl_xor(acc, 32));        // full sums, chan 4q..4q+3
        const float inv = 1.0f / (float)((e - s) > 0 ? (e - s) : 1);
        float4 mean;
        mean.x = acc.x * inv; mean.y = acc.y * inv;
        mean.z = acc.z * inv; mean.w = acc.w * inv;

        // GEMM: c = tanh(mean @ W). Split-K: half h covers k in [64h, 64h+64).
        float4 p = {0.f, 0.f, 0.f, 0.f};
#pragma unroll
        for (int j = 0; j < 16; ++j) {
            const int src = (h << 4) + j;             // lane holding mean[k0..k0+3]
            const float mx = __shfl(mean.x, src, 64);
            const float my = __shfl(mean.y, src, 64);
            const float mz = __shfl(mean.z, src, 64);
            const float mw = __shfl(mean.w, src, 64);
            const int k0 = (h << 6) + (j << 2);
            const float4 w0 = sW4[(k0 + 0) * 32 + q];
            const float4 w1 = sW4[(k0 + 1) * 32 + q];
            const float4 w2 = sW4[(k0 + 2) * 32 + q];
            const float4 w3 = sW4[(k0 + 3) * 32 + q];
            p.x = fmaf(mx, w0.x, p.x); p.y = fmaf(mx, w0.y, p.y);
            p.z = fmaf(mx, w0.z, p.z); p.w = fmaf(mx, w0.w, p.w);
            p.x = fmaf(my, w1.x, p.x); p.y = fmaf(my, w1.y, p.y);
            p.z = fmaf(my, w1.z, p.z); p.w = fmaf(my, w1.w, p.w);
            p.x = fmaf(mz, w2.x, p.x); p.y = fmaf(mz, w2.y, p.y);
            p.z = fmaf(mz, w2.z, p.z); p.w = fmaf(mz, w2.w, p.w);
            p.x = fmaf(mw, w3.x, p.x); p.y = fmaf(mw, w3.y, p.y);
            p.z = fmaf(mw, w3.z, p.z); p.w = fmaf(mw, w3.w, p.w);
        }
        p = f4add(p, f4shfl_xor(p, 32));              // combine the two K-halves
        float4 cv;
        cv.x = tanhf(p.x); cv.y = tanhf(p.y); cv.z = tanhf(p.z); cv.w = tanhf(p.w);

        // pass 2: gate = sigmoid(x_i . c); h += gate * x_i  (rows hot in L2/L3)
        float4 hacc = {0.f, 0.f, 0.f, 0.f};
        for (int i = s + h; i < e; i += 2) {
            float4 v = x4[(size_t)i * 32 + q];
            float d = v.x * cv.x + v.y * cv.y + v.z * cv.z + v.w * cv.w;
            d += __shfl_xor(d, 16, 64);               // reduce within 32-lane half
            d += __shfl_xor(d,  8, 64);
            d += __shfl_xor(d,  4, 64);
            d += __shfl_xor(d,  2, 64);
            d += __shfl_xor(d,  1, 64);
            const float g = 1.0f / (1.0f + __expf(-d));
            hacc.x = fmaf(g, v.x, hacc.x);
            hacc.y = fmaf(g, v.y, hacc.y);
            hacc.z = fmaf(g, v.z, hacc.z);
            hacc.w = fmaf(g, v.w, hacc.w);
        }
        hacc = f4add(hacc, f4shfl_xor(hacc, 32));
        if (lane < 32)
            ((float4*)out)[(size_t)b * 32 + q] = hacc;
    }
}

extern "C" void kernel_launch(void* const* d_in, const int* in_sizes, int n_in,
                              void* d_out, int out_size, void* d_ws, size_t ws_size,
                              hipStream_t stream) {
    const float* x     = (const float*)d_in[0];
    const float* W     = (const float*)d_in[1];
    const int*   batch = (const int*)d_in[2];
    float*       out   = (float*)d_out;

    const int N = in_sizes[0] / C;   // 2,000,000
    const int B = out_size / C;      // 50,000

    const int grid       = 512;                 // 2 blocks/CU resident
    const int totalWaves = grid * WPB;          // 8192 waves, ~6 segments each
    hipLaunchKernelGGL(cba_wave_kernel, dim3(grid), dim3(BLK), 0, stream,
                       x, W, batch, out, N, B, totalWaves);
}